// Round 7
// baseline (77.930 us; speedup 1.0000x reference)
//
#include <hip/hip_runtime.h>

#define BB 8
#define HH 256
#define WW 256
#define NTOT (BB * HH * WW)   // 524288
#define RPB 8                 // rows per block in mega kernel
#define NBLK (BB * HH / RPB)  // 256 blocks = 1 per CU

// ------- Kernel 1 (mega): self-built masks + vertical EDT + pruned
//         exact horizontal min + fused elementwise + block reduce ---------
// Block = RPB consecutive rows of one image. Each block rebuilds the 256-bit
// column masks for its image directly from target (L2-resident redundant
// reads; no inter-block dependency -> no fences/atomics). Pruning
// exactness: k=j gives dt2(j) <= g2(j), so any argmin k* has |j-k*| <= d_j;
// scanning |delta| <= R with R = block_max over all RPB rows of min(d,255)
// is >= each row's own max -> exact. s_g2 rows carry sentinel margins so
// the scan needs no bounds check.
__global__ __launch_bounds__(256) void mega_kernel(
    const float* __restrict__ logits, const float* __restrict__ target,
    float* __restrict__ partials /* [5][NBLK] */) {
  __shared__ float s_g2[RPB][3 * WW];  // [pad | row | pad]
  __shared__ float s_red[4 * 5];
  __shared__ int s_im[4 * 2];  // per-wave {any, rmax}

  const int g = blockIdx.x;        // 0..255
  const int b = g >> 5;            // 32 blocks per image
  const int i0 = (g & 31) * RPB;   // first row within image
  const int j = threadIdx.x;       // column
  const int lane = j & 63, wave = j >> 6;

  // build this column's 256-bit foreground mask from target directly
  const float* col = target + b * (HH * WW) + j;
  unsigned m[8];
#pragma unroll
  for (int w = 0; w < 8; ++w) {
    unsigned mw = 0;
#pragma unroll
    for (int r = 0; r < 32; ++r)
      if (col[(w * 32 + r) * WW] > 0.5f) mw |= (1u << r);
    m[w] = mw;
  }
  const unsigned many = m[0] | m[1] | m[2] | m[3] | m[4] | m[5] | m[6] | m[7];

  // vertical distances for RPB rows; sentinel pads; track scan radius
  int rmax = 0;
#pragma unroll
  for (int r = 0; r < RPB; ++r) {
    const int i = i0 + r;
    const int wi = i >> 5, rr = i & 31;
    int dUp = 1 << 30, dDn = 1 << 30;
    const unsigned cur = m[wi] >> rr;  // bits at rows >= i
    if (cur) {
      dUp = __builtin_ctz(cur);
    } else {
      int off = 32 - rr;
      for (int w2 = wi + 1; w2 < 8; ++w2, off += 32)
        if (m[w2]) { dUp = off + __builtin_ctz(m[w2]); break; }
    }
    const unsigned curd = m[wi] << (31 - rr);  // bits at rows <= i
    if (curd) {
      dDn = __builtin_clz(curd);
    } else {
      int off = rr + 1;
      for (int w2 = wi - 1; w2 >= 0; --w2, off += 32)
        if (m[w2]) { dDn = off + __builtin_clz(m[w2]); break; }
    }
    const int d = min(dUp, dDn);
    s_g2[r][WW + j] = (d < 256) ? (float)(d * d) : 1.0e9f;
    s_g2[r][j] = 1.0e9f;           // left pad
    s_g2[r][2 * WW + j] = 1.0e9f;  // right pad
    rmax = max(rmax, min(d, 255));
  }

  const int wave_any = __any(many != 0u);
#pragma unroll
  for (int off = 32; off > 0; off >>= 1)
    rmax = max(rmax, __shfl_down(rmax, off, 64));
  if (lane == 0) { s_im[wave * 2] = wave_any; s_im[wave * 2 + 1] = rmax; }
  __syncthreads();
  const int nonempty = s_im[0] | s_im[2] | s_im[4] | s_im[6];
  const int R = max(max(s_im[1], s_im[3]), max(s_im[5], s_im[7]));

  // per-row pruned horizontal min + fused elementwise, accumulated locally
  float v0 = 0.f, v1 = 0.f, v2 = 0.f, v3 = 0.f, v4 = 0.f;
#pragma unroll
  for (int r = 0; r < RPB; ++r) {
    float mn = 1.0e30f;
    const float* gp = &s_g2[r][WW + j];
    for (int dlt = -R; dlt <= R; ++dlt)
      mn = fminf(mn, (float)(dlt * dlt) + gp[dlt]);
    const float dt = nonempty ? sqrtf(mn) : 0.0f;

    const int idx = (b * HH + i0 + r) * WW + j;
    const float x = logits[idx];
    float t = target[idx];
    t = fminf(fmaxf(t, 0.0f), 1.0f);
    const float e = __expf(-fabsf(x));
    const float inv = 1.0f / (1.0f + e);
    const float ce = fmaxf(x, 0.0f) + __logf(1.0f + e) - x * t;
    float p = (x >= 0.0f) ? inv : e * inv;  // sigmoid
    p = fminf(fmaxf(p, 1e-6f), 1.0f - 1e-6f);
    v0 += ce; v1 += p; v2 += t; v3 += p * t; v4 += p * dt;
  }

  // block reduce (fp32) -> plain per-block partial stores
  float v[5] = {v0, v1, v2, v3, v4};
#pragma unroll
  for (int q = 0; q < 5; ++q) {
    float s = v[q];
#pragma unroll
    for (int off = 32; off > 0; off >>= 1) s += __shfl_down(s, off, 64);
    if (lane == 0) s_red[wave * 5 + q] = s;
  }
  __syncthreads();
  if (j == 0) {
#pragma unroll
    for (int q = 0; q < 5; ++q)
      partials[q * NBLK + g] =
          s_red[q] + s_red[5 + q] + s_red[10 + q] + s_red[15 + q];
  }
}

// ---------------- Kernel 2: final reduction (double) + loss math -----------
__global__ __launch_bounds__(256) void finalize(
    const float* __restrict__ partials, float* __restrict__ out) {
  __shared__ double s_red[4 * 5];
  const int j = threadIdx.x;  // 256 threads, one partial each
  const int lane = j & 63, wave = j >> 6;
  double acc[5];
#pragma unroll
  for (int q = 0; q < 5; ++q) acc[q] = (double)partials[q * NBLK + j];
#pragma unroll
  for (int q = 0; q < 5; ++q) {
    double s = acc[q];
#pragma unroll
    for (int off = 32; off > 0; off >>= 1) s += __shfl_down(s, off, 64);
    if (lane == 0) s_red[wave * 5 + q] = s;
  }
  __syncthreads();
  if (j == 0) {
    double sum[5];
#pragma unroll
    for (int q = 0; q < 5; ++q)
      sum[q] = s_red[q] + s_red[5 + q] + s_red[10 + q] + s_red[15 + q];
    const double n = (double)NTOT;
    const double ce = sum[0] / n;
    const double dice = 1.0 - (2.0 * sum[3] + 1e-6) / (sum[1] + sum[2] + 1e-6);
    const double boundary = sum[4] / n;
    out[0] = (float)(ce + dice + 0.1 * boundary);
    out[1] = (float)ce;
    out[2] = (float)dice;
    out[3] = (float)boundary;
  }
}

extern "C" void kernel_launch(void* const* d_in, const int* in_sizes, int n_in,
                              void* d_out, int out_size, void* d_ws,
                              size_t ws_size, hipStream_t stream) {
  const float* logits = (const float*)d_in[0];
  const float* target = (const float*)d_in[1];
  float* out = (float*)d_out;

  float* partials = (float*)d_ws;  // 5*256*4 = 5 KB

  mega_kernel<<<NBLK, 256, 0, stream>>>(logits, target, partials);
  finalize<<<1, 256, 0, stream>>>(partials, out);
}